// Round 5
// baseline (263.769 us; speedup 1.0000x reference)
//
#include <hip/hip_runtime.h>
#include <cstdint>

// Problem constants: B=16, S=1, Dm=4096, H=32, Hd=128, P=2048
#define DM 4096
#define NB 16
#define NH 32
#define HD 128
#define PP 2048
#define NCHUNK 32
#define CROWS 64     // PP / NCHUNK
#define PSTRIDE 132  // per-head partial: 128 o + m + s + 2 pad

typedef __attribute__((ext_vector_type(8))) short bf16x8;
typedef __attribute__((ext_vector_type(4))) float f32x4;

__device__ inline float bf2f(short s) {
  return __uint_as_float(((uint32_t)(uint16_t)s) << 16);
}
__device__ inline f32x4 ntld4(const float* p) {
  return __builtin_nontemporal_load(reinterpret_cast<const f32x4*>(p));
}

// Pairwise truncation hi/lo bf16 split:
//   hi = trunc16(x) (1 v_perm per pair), lo = x - hi (exact), lo -> bf16 RNE
//   (1 v_cvt_pk_bf16_f32 per pair). dst dword = {elem0 lo16, elem1 hi16}.
__device__ inline void split_pair(float x0, float x1, uint32_t& hpair,
                                  uint32_t& lpair) {
  uint32_t u0 = __float_as_uint(x0), u1 = __float_as_uint(x1);
  hpair = __builtin_amdgcn_perm(u1, u0, 0x07060302u);
  float l0 = x0 - __uint_as_float(u0 & 0xFFFF0000u);
  float l1 = x1 - __uint_as_float(u1 & 0xFFFF0000u);
  asm("v_cvt_pk_bf16_f32 %0, %1, %2" : "=v"(lpair) : "v"(l0), "v"(l1));
}

// O[b][col(jt+n)] = sum_d A[b][d] * W[jt+n][d], 16-wide column tile.
// NW waves split K. ROPE: rotary remap applied to the output columns.
template <int NW, bool ROPE>
__device__ inline void gemv16(const float* __restrict__ A,
                              const float* __restrict__ W,
                              float* __restrict__ O, int jt,
                              const float* __restrict__ fr,
                              const float* __restrict__ fi) {
  const int wave = threadIdx.x >> 6;
  const int lane = threadIdx.x & 63;
  const int m = lane & 15;   // A-row (batch) / W-row (output col) in tile
  const int kg = lane >> 4;  // k-group 0..3
  const float* arow = A + (size_t)m * DM;
  const float* wrow = W + (size_t)(jt + m) * DM;
  const int kbase = wave * (DM / NW) + kg * 8;
  f32x4 acc = {0.f, 0.f, 0.f, 0.f};
#pragma unroll 2
  for (int kb = 0; kb < (DM / NW) / 32; ++kb) {
    const int k = kbase + kb * 32;
    f32x4 xa = *(const f32x4*)(arow + k);
    f32x4 xb = *(const f32x4*)(arow + k + 4);
    f32x4 wa = ntld4(wrow + k);
    f32x4 wb = ntld4(wrow + k + 4);
    union { bf16x8 v; uint32_t d[4]; } ah, al, wh, wl;
    split_pair(xa.x, xa.y, ah.d[0], al.d[0]);
    split_pair(xa.z, xa.w, ah.d[1], al.d[1]);
    split_pair(xb.x, xb.y, ah.d[2], al.d[2]);
    split_pair(xb.z, xb.w, ah.d[3], al.d[3]);
    split_pair(wa.x, wa.y, wh.d[0], wl.d[0]);
    split_pair(wa.z, wa.w, wh.d[1], wl.d[1]);
    split_pair(wb.x, wb.y, wh.d[2], wl.d[2]);
    split_pair(wb.z, wb.w, wh.d[3], wl.d[3]);
    acc = __builtin_amdgcn_mfma_f32_16x16x32_bf16(ah.v, wh.v, acc, 0, 0, 0);
    acc = __builtin_amdgcn_mfma_f32_16x16x32_bf16(ah.v, wl.v, acc, 0, 0, 0);
    acc = __builtin_amdgcn_mfma_f32_16x16x32_bf16(al.v, wh.v, acc, 0, 0, 0);
  }
  __shared__ float red[NW][256];
  red[wave][lane * 4 + 0] = acc[0];
  red[wave][lane * 4 + 1] = acc[1];
  red[wave][lane * 4 + 2] = acc[2];
  red[wave][lane * 4 + 3] = acc[3];
  __syncthreads();
  const int t = threadIdx.x;
  float s = 0.f;
  if (t < 256) {
#pragma unroll
    for (int w = 0; w < NW; ++w) s += red[w][t];
  }
  float part = 0.f;
  if (ROPE) {
    __syncthreads();
    if (t < 256) red[0][t] = s;
    __syncthreads();
    if (t < 256) part = red[0][t ^ 4];  // pair-partner (adjacent output col)
  }
  if (t < 256) {
    const int l = t >> 2, r = t & 3;
    const int bb = ((l >> 4) << 2) + r;  // batch row of D
    const int n = l & 15;                // column within tile
    const int c = jt + n;
    float val;
    int oc;
    if (ROPE) {
      const int j = (c & 127) >> 1;
      const float f_r = fr[j], f_i = fi[j];
      if ((c & 1) == 0) {  // even col: s = x_even, part = x_odd
        val = s * f_r - part * f_i;
        oc = (c & ~127) + j;
      } else {             // odd col: part = x_even, s = x_odd
        val = part * f_i + s * f_r;
        oc = (c & ~127) + 64 + j;
      }
    } else {
      val = s;
      oc = c;
    }
    O[(size_t)bb * DM + oc] = val;
  }
}

__global__ __launch_bounds__(256) void qkv_proj_kernel(
    const float* __restrict__ x, const float* __restrict__ wq,
    const float* __restrict__ wk, const float* __restrict__ wv,
    const float* __restrict__ fr, const float* __restrict__ fi,
    float* __restrict__ oq, float* __restrict__ ok, float* __restrict__ ov) {
  const int g = blockIdx.x >> 8;
  const int jt = (blockIdx.x & 255) << 4;
  if (g == 0)
    gemv16<4, true>(x, wq, oq, jt, fr, fi);
  else if (g == 1)
    gemv16<4, true>(x, wk, ok, jt, fr, fi);
  else
    gemv16<4, false>(x, wv, ov, jt, nullptr, nullptr);
}

__global__ __launch_bounds__(1024, 4) void oproj_kernel(
    const float* __restrict__ a, const float* __restrict__ w,
    float* __restrict__ o) {
  gemv16<16, false>(a, w, o, blockIdx.x << 4, nullptr, nullptr);
}

// One block per (b, chunk): streams K[b][c*64..+64][*][*] (1MB contiguous) then
// V likewise. Thread t owns head t>>4, dims [(t&15)*8, +8) -> contiguous
// float8 per thread, 4-stage 16-lane DPP reduction for scores.
__global__ __launch_bounds__(512) void attn_chunk_kernel(
    const float* __restrict__ qrope, const float* __restrict__ cache_k,
    const float* __restrict__ cache_v, float* __restrict__ part) {
  const int b = blockIdx.x >> 5;
  const int c = blockIdx.x & 31;
  const int t = threadIdx.x;
  const int hh = t >> 4;  // head 0..31
  const int u = t & 15;   // 16 threads per head
  __shared__ float sc[NH][CROWS];

  const float* qp = qrope + (size_t)b * DM + hh * HD + u * 8;
  const f32x4 qa = *(const f32x4*)(qp);
  const f32x4 qb = *(const f32x4*)(qp + 4);
  const float scale = 0.08838834764831845f;  // 1/sqrt(128)

  const float* Kb =
      cache_k + ((size_t)b * PP + (size_t)c * CROWS) * DM + hh * HD + u * 8;
#pragma unroll 2
  for (int r = 0; r < CROWS; ++r) {
    const float* krow = Kb + (size_t)r * DM;
    f32x4 k1 = ntld4(krow);
    f32x4 k2 = ntld4(krow + 4);
    float p = qa.x * k1.x + qa.y * k1.y + qa.z * k1.z + qa.w * k1.w +
              qb.x * k2.x + qb.y * k2.y + qb.z * k2.z + qb.w * k2.w;
    p += __shfl_xor(p, 1);
    p += __shfl_xor(p, 2);
    p += __shfl_xor(p, 4);
    p += __shfl_xor(p, 8);
    if (u == 0) sc[hh][r] = p * scale;
  }
  __syncthreads();

  // per-head chunk-local softmax: 16 threads per head, 4 scores each
  float4 sv4 = *(const float4*)(&sc[hh][u * 4]);
  float mx = fmaxf(fmaxf(sv4.x, sv4.y), fmaxf(sv4.z, sv4.w));
#pragma unroll
  for (int off = 1; off <= 8; off <<= 1) mx = fmaxf(mx, __shfl_xor(mx, off));
  float e0 = __expf(sv4.x - mx), e1 = __expf(sv4.y - mx);
  float e2 = __expf(sv4.z - mx), e3 = __expf(sv4.w - mx);
  float4 ev = {e0, e1, e2, e3};
  *(float4*)(&sc[hh][u * 4]) = ev;
  float sm = (e0 + e1) + (e2 + e3);
#pragma unroll
  for (int off = 1; off <= 8; off <<= 1) sm += __shfl_xor(sm, off);
  float* pb = part + ((size_t)(b * NCHUNK + c) * NH) * PSTRIDE;
  if (u == 0) {
    pb[hh * PSTRIDE + 128] = mx;
    pb[hh * PSTRIDE + 129] = sm;
  }
  __syncthreads();

  // PV: same thread->head/dim mapping
  const float* Vb =
      cache_v + ((size_t)b * PP + (size_t)c * CROWS) * DM + hh * HD + u * 8;
  f32x4 a1 = {0.f, 0.f, 0.f, 0.f}, a2 = {0.f, 0.f, 0.f, 0.f};
#pragma unroll 2
  for (int r = 0; r < CROWS; ++r) {
    const float* vrow = Vb + (size_t)r * DM;
    f32x4 v1 = ntld4(vrow);
    f32x4 v2 = ntld4(vrow + 4);
    float w = sc[hh][r];
    a1 += w * v1;
    a2 += w * v2;
  }
  *(f32x4*)(pb + hh * PSTRIDE + u * 8) = a1;
  *(f32x4*)(pb + hh * PSTRIDE + u * 8 + 4) = a2;
}

// One block per (b, h): merge 32 chunk partials + the appended position.
__global__ __launch_bounds__(128) void attn_combine_kernel(
    const float* __restrict__ qrope, const float* __restrict__ krope,
    const float* __restrict__ vraw, const float* __restrict__ part,
    float* __restrict__ aout) {
  const int b = blockIdx.x >> 5;
  const int h = blockIdx.x & 31;
  const int d = threadIdx.x;
  __shared__ float red2[2];
  __shared__ float mv[NCHUNK], sv[NCHUNK], ec[NCHUNK];
  const size_t qoff = (size_t)b * DM + h * HD + d;
  float p = qrope[qoff] * krope[qoff];
#pragma unroll
  for (int off = 1; off <= 32; off <<= 1) p += __shfl_xor(p, off);
  if ((d & 63) == 0) red2[d >> 6] = p;
  const float* pb = part + ((size_t)b * NCHUNK * NH + h) * PSTRIDE;
  if (d < NCHUNK) {
    mv[d] = pb[(size_t)d * NH * PSTRIDE + 128];
    sv[d] = pb[(size_t)d * NH * PSTRIDE + 129];
  }
  __syncthreads();
  const float scale = 0.08838834764831845f;
  const float snew = (red2[0] + red2[1]) * scale;
  float M = snew;
#pragma unroll
  for (int c = 0; c < NCHUNK; ++c) M = fmaxf(M, mv[c]);
  if (d < NCHUNK) ec[d] = __expf(mv[d] - M);
  __syncthreads();
  const float en = __expf(snew - M);
  float S = en;
  float acc = en * vraw[qoff];
#pragma unroll 4
  for (int c = 0; c < NCHUNK; ++c) {
    acc += ec[c] * pb[(size_t)c * NH * PSTRIDE + d];
    S += ec[c] * sv[c];
  }
  aout[qoff] = acc / S;
}

extern "C" void kernel_launch(void* const* d_in, const int* in_sizes, int n_in,
                              void* d_out, int out_size, void* d_ws, size_t ws_size,
                              hipStream_t stream) {
  const float* x = (const float*)d_in[0];
  const float* cache_k = (const float*)d_in[1];
  const float* cache_v = (const float*)d_in[2];
  const float* fr = (const float*)d_in[3];
  const float* fi = (const float*)d_in[4];
  const float* dwq = (const float*)d_in[5];
  const float* dwk = (const float*)d_in[6];
  const float* dwv = (const float*)d_in[7];
  const float* dwo = (const float*)d_in[8];
  float* out = (float*)d_out;

  float* qrope = (float*)d_ws;          // 16*4096 (RoPE'd q, final layout)
  float* krope = qrope + NB * DM;       // 16*4096 (RoPE'd new k)
  float* vraw = krope + NB * DM;        // 16*4096 (new v)
  float* aout = vraw + NB * DM;         // 16*4096 (attention output)
  float* part = aout + NB * DM;         // 16*32*32*132 chunk partials

  qkv_proj_kernel<<<768, 256, 0, stream>>>(x, dwq, dwk, dwv, fr, fi,
                                           qrope, krope, vraw);
  attn_chunk_kernel<<<512, 512, 0, stream>>>(qrope, cache_k, cache_v, part);
  attn_combine_kernel<<<512, 128, 0, stream>>>(qrope, krope, vraw, part, aout);
  oproj_kernel<<<256, 1024, 0, stream>>>(aout, dwo, out);
}

// Round 6
// 241.180 us; speedup vs baseline: 1.0937x; 1.0937x over previous
//
#include <hip/hip_runtime.h>
#include <cstdint>

// Problem constants: B=16, S=1, Dm=4096, H=32, Hd=128, P=2048
#define DM 4096
#define NB 16
#define NH 32
#define HD 128
#define PP 2048
#define NCHUNK 32
#define CROWS 64     // PP / NCHUNK
#define PSTRIDE 132  // per-head partial: 128 o + m + s + 2 pad

typedef __attribute__((ext_vector_type(8))) short bf16x8;
typedef __attribute__((ext_vector_type(4))) float f32x4;

__device__ inline float bf2f(short s) {
  return __uint_as_float(((uint32_t)(uint16_t)s) << 16);
}
__device__ inline f32x4 ntld4(const float* p) {
  return __builtin_nontemporal_load(reinterpret_cast<const f32x4*>(p));
}

// Pairwise truncation hi/lo bf16 split:
//   hi = trunc16(x) (1 v_perm per pair), lo = x - hi (exact), lo -> bf16 RNE
//   (1 v_cvt_pk_bf16_f32 per pair). dst dword = {elem0 lo16, elem1 hi16}.
__device__ inline void split_pair(float x0, float x1, uint32_t& hpair,
                                  uint32_t& lpair) {
  uint32_t u0 = __float_as_uint(x0), u1 = __float_as_uint(x1);
  hpair = __builtin_amdgcn_perm(u1, u0, 0x07060302u);
  float l0 = x0 - __uint_as_float(u0 & 0xFFFF0000u);
  float l1 = x1 - __uint_as_float(u1 & 0xFFFF0000u);
  asm("v_cvt_pk_bf16_f32 %0, %1, %2" : "=v"(lpair) : "v"(l0), "v"(l1));
}

// O[b][col(jt+n)] = sum_d A[b][d] * W[jt+n][d], 16-wide column tile.
// NW waves split K. ROPE: rotary remap applied to the output columns.
template <int NW, bool ROPE>
__device__ inline void gemv16(const float* __restrict__ A,
                              const float* __restrict__ W,
                              float* __restrict__ O, int jt,
                              const float* __restrict__ fr,
                              const float* __restrict__ fi) {
  const int wave = threadIdx.x >> 6;
  const int lane = threadIdx.x & 63;
  const int m = lane & 15;   // A-row (batch) / W-row (output col) in tile
  const int kg = lane >> 4;  // k-group 0..3
  const float* arow = A + (size_t)m * DM;
  const float* wrow = W + (size_t)(jt + m) * DM;
  const int kbase = wave * (DM / NW) + kg * 8;
  f32x4 acc = {0.f, 0.f, 0.f, 0.f};
#pragma unroll 2
  for (int kb = 0; kb < (DM / NW) / 32; ++kb) {
    const int k = kbase + kb * 32;
    f32x4 xa = *(const f32x4*)(arow + k);
    f32x4 xb = *(const f32x4*)(arow + k + 4);
    f32x4 wa = ntld4(wrow + k);
    f32x4 wb = ntld4(wrow + k + 4);
    union { bf16x8 v; uint32_t d[4]; } ah, al, wh, wl;
    split_pair(xa.x, xa.y, ah.d[0], al.d[0]);
    split_pair(xa.z, xa.w, ah.d[1], al.d[1]);
    split_pair(xb.x, xb.y, ah.d[2], al.d[2]);
    split_pair(xb.z, xb.w, ah.d[3], al.d[3]);
    split_pair(wa.x, wa.y, wh.d[0], wl.d[0]);
    split_pair(wa.z, wa.w, wh.d[1], wl.d[1]);
    split_pair(wb.x, wb.y, wh.d[2], wl.d[2]);
    split_pair(wb.z, wb.w, wh.d[3], wl.d[3]);
    acc = __builtin_amdgcn_mfma_f32_16x16x32_bf16(ah.v, wh.v, acc, 0, 0, 0);
    acc = __builtin_amdgcn_mfma_f32_16x16x32_bf16(ah.v, wl.v, acc, 0, 0, 0);
    acc = __builtin_amdgcn_mfma_f32_16x16x32_bf16(al.v, wh.v, acc, 0, 0, 0);
  }
  __shared__ float red[NW][256];
  red[wave][lane * 4 + 0] = acc[0];
  red[wave][lane * 4 + 1] = acc[1];
  red[wave][lane * 4 + 2] = acc[2];
  red[wave][lane * 4 + 3] = acc[3];
  __syncthreads();
  const int t = threadIdx.x;
  float s = 0.f;
  if (t < 256) {
#pragma unroll
    for (int w = 0; w < NW; ++w) s += red[w][t];
  }
  float part = 0.f;
  if (ROPE) {
    __syncthreads();
    if (t < 256) red[0][t] = s;
    __syncthreads();
    if (t < 256) part = red[0][t ^ 4];  // pair-partner (adjacent output col)
  }
  if (t < 256) {
    const int l = t >> 2, r = t & 3;
    const int bb = ((l >> 4) << 2) + r;  // batch row of D
    const int n = l & 15;                // column within tile
    const int c = jt + n;
    float val;
    int oc;
    if (ROPE) {
      const int j = (c & 127) >> 1;
      const float f_r = fr[j], f_i = fi[j];
      if ((c & 1) == 0) {  // even col: s = x_even, part = x_odd
        val = s * f_r - part * f_i;
        oc = (c & ~127) + j;
      } else {             // odd col: part = x_even, s = x_odd
        val = part * f_i + s * f_r;
        oc = (c & ~127) + 64 + j;
      }
    } else {
      val = s;
      oc = c;
    }
    O[(size_t)bb * DM + oc] = val;
  }
}

__global__ __launch_bounds__(256) void qkv_proj_kernel(
    const float* __restrict__ x, const float* __restrict__ wq,
    const float* __restrict__ wk, const float* __restrict__ wv,
    const float* __restrict__ fr, const float* __restrict__ fi,
    float* __restrict__ oq, float* __restrict__ ok, float* __restrict__ ov) {
  const int g = blockIdx.x >> 8;
  const int jt = (blockIdx.x & 255) << 4;
  if (g == 0)
    gemv16<4, true>(x, wq, oq, jt, fr, fi);
  else if (g == 1)
    gemv16<4, true>(x, wk, ok, jt, fr, fi);
  else
    gemv16<4, false>(x, wv, ov, jt, nullptr, nullptr);
}

__global__ __launch_bounds__(1024, 4) void oproj_kernel(
    const float* __restrict__ a, const float* __restrict__ w,
    float* __restrict__ o) {
  gemv16<16, false>(a, w, o, blockIdx.x << 4, nullptr, nullptr);
}

// One block per (b, chunk): streams K[b][c*64..+64][*][*] (1MB contiguous) then
// V likewise. Wave-contiguous loads: thread t reads float4 at 4t and 4t+2048
// (heads t>>5 and (t>>5)+16) -> every load instruction covers a contiguous
// 1KB-per-wave segment. 32-lane shuffle reductions (VALU is ~4% busy; free).
__global__ __launch_bounds__(512) void attn_chunk_kernel(
    const float* __restrict__ qrope, const float* __restrict__ cache_k,
    const float* __restrict__ cache_v, float* __restrict__ part) {
  const int b = blockIdx.x >> 5;
  const int c = blockIdx.x & 31;
  const int t = threadIdx.x;
  __shared__ float sc[NH][CROWS];

  const f32x4 qa = *(const f32x4*)(qrope + (size_t)b * DM + 4 * t);
  const f32x4 qb = *(const f32x4*)(qrope + (size_t)b * DM + 2048 + 4 * t);
  const int h1 = t >> 5;
  const int h2 = h1 + 16;
  const float scale = 0.08838834764831845f;  // 1/sqrt(128)

  const float* Kb = cache_k + ((size_t)b * PP + (size_t)c * CROWS) * DM;
#pragma unroll 2
  for (int r = 0; r < CROWS; ++r) {
    const float* krow = Kb + (size_t)r * DM + 4 * t;
    f32x4 k1 = ntld4(krow);
    f32x4 k2 = ntld4(krow + 2048);
    float p1 = qa.x * k1.x + qa.y * k1.y + qa.z * k1.z + qa.w * k1.w;
    float p2 = qb.x * k2.x + qb.y * k2.y + qb.z * k2.z + qb.w * k2.w;
#pragma unroll
    for (int off = 1; off <= 16; off <<= 1) {
      p1 += __shfl_xor(p1, off);
      p2 += __shfl_xor(p2, off);
    }
    if ((t & 31) == 0) {
      sc[h1][r] = p1 * scale;
      sc[h2][r] = p2 * scale;
    }
  }
  __syncthreads();

  // per-head chunk-local softmax: 16 threads per head, 4 scores each
  const int hh = t >> 4, u = t & 15;
  float4 sv4 = *(const float4*)(&sc[hh][u * 4]);
  float mx = fmaxf(fmaxf(sv4.x, sv4.y), fmaxf(sv4.z, sv4.w));
#pragma unroll
  for (int off = 1; off <= 8; off <<= 1) mx = fmaxf(mx, __shfl_xor(mx, off));
  float e0 = __expf(sv4.x - mx), e1 = __expf(sv4.y - mx);
  float e2 = __expf(sv4.z - mx), e3 = __expf(sv4.w - mx);
  float4 ev = {e0, e1, e2, e3};
  *(float4*)(&sc[hh][u * 4]) = ev;  // in-place: e values replace scores
  float sm = (e0 + e1) + (e2 + e3);
#pragma unroll
  for (int off = 1; off <= 8; off <<= 1) sm += __shfl_xor(sm, off);
  float* pb = part + ((size_t)(b * NCHUNK + c) * NH) * PSTRIDE;
  if (u == 0) {
    pb[hh * PSTRIDE + 128] = mx;
    pb[hh * PSTRIDE + 129] = sm;
  }
  __syncthreads();

  // PV: same thread->dim mapping as score phase
  const float* Vb = cache_v + ((size_t)b * PP + (size_t)c * CROWS) * DM;
  f32x4 a1 = {0.f, 0.f, 0.f, 0.f}, a2 = {0.f, 0.f, 0.f, 0.f};
#pragma unroll 2
  for (int r = 0; r < CROWS; ++r) {
    const float* vrow = Vb + (size_t)r * DM + 4 * t;
    f32x4 v1 = ntld4(vrow);
    f32x4 v2 = ntld4(vrow + 2048);
    float w1 = sc[h1][r], w2 = sc[h2][r];
    a1 += w1 * v1;
    a2 += w2 * v2;
  }
  const int dbase = (4 * t) & 127;
  *(f32x4*)(pb + h1 * PSTRIDE + dbase) = a1;
  *(f32x4*)(pb + h2 * PSTRIDE + dbase) = a2;
}

// One block per (b, h): merge 32 chunk partials + the appended position.
__global__ __launch_bounds__(128) void attn_combine_kernel(
    const float* __restrict__ qrope, const float* __restrict__ krope,
    const float* __restrict__ vraw, const float* __restrict__ part,
    float* __restrict__ aout) {
  const int b = blockIdx.x >> 5;
  const int h = blockIdx.x & 31;
  const int d = threadIdx.x;
  __shared__ float red2[2];
  __shared__ float mv[NCHUNK], sv[NCHUNK], ec[NCHUNK];
  const size_t qoff = (size_t)b * DM + h * HD + d;
  float p = qrope[qoff] * krope[qoff];
#pragma unroll
  for (int off = 1; off <= 32; off <<= 1) p += __shfl_xor(p, off);
  if ((d & 63) == 0) red2[d >> 6] = p;
  const float* pb = part + ((size_t)b * NCHUNK * NH + h) * PSTRIDE;
  if (d < NCHUNK) {
    mv[d] = pb[(size_t)d * NH * PSTRIDE + 128];
    sv[d] = pb[(size_t)d * NH * PSTRIDE + 129];
  }
  __syncthreads();
  const float scale = 0.08838834764831845f;
  const float snew = (red2[0] + red2[1]) * scale;
  float M = snew;
#pragma unroll
  for (int c = 0; c < NCHUNK; ++c) M = fmaxf(M, mv[c]);
  if (d < NCHUNK) ec[d] = __expf(mv[d] - M);
  __syncthreads();
  const float en = __expf(snew - M);
  float S = en;
  float acc = en * vraw[qoff];
#pragma unroll 4
  for (int c = 0; c < NCHUNK; ++c) {
    acc += ec[c] * pb[(size_t)c * NH * PSTRIDE + d];
    S += ec[c] * sv[c];
  }
  aout[qoff] = acc / S;
}

extern "C" void kernel_launch(void* const* d_in, const int* in_sizes, int n_in,
                              void* d_out, int out_size, void* d_ws, size_t ws_size,
                              hipStream_t stream) {
  const float* x = (const float*)d_in[0];
  const float* cache_k = (const float*)d_in[1];
  const float* cache_v = (const float*)d_in[2];
  const float* fr = (const float*)d_in[3];
  const float* fi = (const float*)d_in[4];
  const float* dwq = (const float*)d_in[5];
  const float* dwk = (const float*)d_in[6];
  const float* dwv = (const float*)d_in[7];
  const float* dwo = (const float*)d_in[8];
  float* out = (float*)d_out;

  float* qrope = (float*)d_ws;          // 16*4096 (RoPE'd q, final layout)
  float* krope = qrope + NB * DM;       // 16*4096 (RoPE'd new k)
  float* vraw = krope + NB * DM;        // 16*4096 (new v)
  float* aout = vraw + NB * DM;         // 16*4096 (attention output)
  float* part = aout + NB * DM;         // 16*32*32*132 chunk partials

  qkv_proj_kernel<<<768, 256, 0, stream>>>(x, dwq, dwk, dwv, fr, fi,
                                           qrope, krope, vraw);
  attn_chunk_kernel<<<512, 512, 0, stream>>>(qrope, cache_k, cache_v, part);
  attn_combine_kernel<<<512, 128, 0, stream>>>(qrope, krope, vraw, part, aout);
  oproj_kernel<<<256, 1024, 0, stream>>>(aout, dwo, out);
}